// Round 5
// baseline (413.101 us; speedup 1.0000x reference)
//
#include <hip/hip_runtime.h>

#define TINY 1e-6f

constexpr int N_PIX = 256 * 512;   // 131072 pixels, S = 64 samples
constexpr int TILE  = 16;          // pixels per block
constexpr int PPAD  = 196;         // padded floats per pixel slot (192 + 4)

__device__ __forceinline__ float clamp01(float x) {
    return fminf(fmaxf(x, 0.0f), 1.0f);
}

__device__ __forceinline__ float frcp(float x) {
    return __builtin_amdgcn_rcpf(x);
}

// Staging with m13-copy geometry: per array, the block's 16-pixel tile is
// 12288 B; thread t loads float4 index {c*256+t | c=0..2} -- lane i at byte
// 16*i of a contiguous 4 KB span per instruction (global_load_dwordx4,
// zero holes). This is the exact geometry that achieves 6.29 TB/s in the
// copy microbenchmark; if adjacent-line merging is what doubles request
// efficiency there, it applies here too. sched_barrier(0) pins all 12
// loads above the ds_writes so the scheduler cannot sink them into a
// serial load->write->load chain (the VGPR=32 pathology of R1-R4).
// LDS layout pads each pixel to 196 floats to spread the 4 pixel-groups
// of a wave across banks during the compute-phase 12 B reads.
__global__ void __launch_bounds__(256, 3)
shade_kernel(const float* __restrict__ normal,
             const float* __restrict__ albedo,
             const float* __restrict__ roughness,
             const float* __restrict__ points,
             const float* __restrict__ cam,
             const float* __restrict__ ldir,
             const float* __restrict__ dlight,
             const float* __restrict__ hdir,
             const float* __restrict__ slight,
             float* __restrict__ out)
{
    __shared__ float lds[4][TILE * PPAD];   // 4 x 12544 B = 50176 B

    const int t      = threadIdx.x;
    const int stage0 = blockIdx.x * TILE;

    // ---- phase 1: 12 coalesced dwordx4 loads, all in flight ----
    const float* garr[4] = { ldir, dlight, hdir, slight };
    float4 v[4][3];
#pragma unroll
    for (int a = 0; a < 4; ++a) {
        const float4* g = (const float4*)(garr[a] + (size_t)stage0 * 192);
#pragma unroll
        for (int c = 0; c < 3; ++c)
            v[a][c] = g[c * 256 + t];
    }
    __builtin_amdgcn_sched_barrier(0);   // keep the load batch above the writes

    // ---- phase 2: scatter to padded LDS (16 B aligned, ~conflict-free) ----
#pragma unroll
    for (int a = 0; a < 4; ++a) {
#pragma unroll
        for (int c = 0; c < 3; ++c) {
            const int f   = c * 256 + t;     // float4 index in tile (0..767)
            const int p   = f / 48;          // pixel (48 float4 per pixel)
            const int rem = f - p * 48;
            *(float4*)&lds[a][p * PPAD + rem * 4] = v[a][c];
        }
    }

    // ---- per-pixel constants (overlap with LDS-write drain) ----
    const int w    = t >> 6;
    const int lane = t & 63;
    const int grp  = lane >> 4;
    const int sub  = lane & 15;
    const int pin  = w * 4 + grp;          // pixel within tile
    const int pix  = stage0 + pin;

    const float nx = normal[pix * 3 + 0];
    const float ny = normal[pix * 3 + 1];
    const float nz = normal[pix * 3 + 2];
    const float r  = roughness[pix];
    const float px = points[pix * 3 + 0];
    const float py = points[pix * 3 + 1];
    const float pz = points[pix * 3 + 2];
    const float cx = cam[0], cy = cam[1], cz = cam[2];

    const float dx = cx - px, dy = cy - py, dz = cz - pz;
    const float len = sqrtf(dx * dx + dy * dy + dz * dz);
    const float inv = frcp(fmaxf(len, 1e-4f));
    const float vx = dx * inv, vy = dy * inv, vz = dz * inv;

    const float ndv = clamp01(nx * vx + ny * vy + nz * vz);
    const float k1  = (r + 1.0f) * (r + 1.0f) * 0.125f;
    const float omk = 1.0f - k1;
    const float g1v = ndv * frcp(fmaxf(ndv * omk + k1, TINY));

    __syncthreads();

    // ---- phase 3: compute from LDS (identical math to R4) ----
    const float* Lb = &lds[0][pin * PPAD];
    const float* Db = &lds[1][pin * PPAD];
    const float* Hb = &lds[2][pin * PPAD];
    const float* Sb = &lds[3][pin * PPAD];

    float dacc0 = 0.f, dacc1 = 0.f, dacc2 = 0.f;
    float sacc0 = 0.f, sacc1 = 0.f, sacc2 = 0.f;

#pragma unroll
    for (int j = 0; j < 4; ++j) {
        const int o = j * 48 + sub * 3;    // sample 16j+sub of this pixel
        const float lx = Lb[o + 0], ly = Lb[o + 1], lz = Lb[o + 2];
        const float d0 = Db[o + 0], d1 = Db[o + 1], d2 = Db[o + 2];
        const float hx = Hb[o + 0], hy = Hb[o + 1], hz = Hb[o + 2];
        const float s0 = Sb[o + 0], s1 = Sb[o + 1], s2 = Sb[o + 2];

        const float ndl_d = clamp01(nx * lx + ny * ly + nz * lz);
        dacc0 += d0 * ndl_d;
        dacc1 += d1 * ndl_d;
        dacc2 += d2 * ndl_d;

        const float vdh = clamp01(hx * vx + hy * vy + hz * vz);
        const float tv  = 2.0f * vdh;
        const float lsx = tv * hx - vx;
        const float lsy = tv * hy - vy;
        const float lsz = tv * hz - vz;
        const float ndl = clamp01(nx * lsx + ny * lsy + nz * lsz);
        const float ndh = clamp01(nx * hx + ny * hy + nz * hz);
        const float f   = 0.04f + 0.96f * exp2f((-5.55472f * vdh - 6.98316f) * vdh);
        const float g1l = ndl * frcp(fmaxf(ndl * omk + k1, TINY));
        const float brdf = f * g1l * g1v * frcp(fmaxf(4.0f * ndl * ndv, TINY));
        const float wgt  = brdf * ndl * 4.0f * vdh * frcp(fmaxf(ndh, TINY));
        sacc0 += s0 * wgt;
        sacc1 += s1 * wgt;
        sacc2 += s2 * wgt;
    }

    // ---- butterfly reduction within each 16-lane group ----
#pragma unroll
    for (int off = 1; off < 16; off <<= 1) {
        dacc0 += __shfl_xor(dacc0, off);
        dacc1 += __shfl_xor(dacc1, off);
        dacc2 += __shfl_xor(dacc2, off);
        sacc0 += __shfl_xor(sacc0, off);
        sacc1 += __shfl_xor(sacc1, off);
        sacc2 += __shfl_xor(sacc2, off);
    }

    if (sub == 0) {
        const float ax = albedo[pix * 3 + 0];
        const float ay = albedo[pix * 3 + 1];
        const float az = albedo[pix * 3 + 2];
        const float inv_s = 1.0f / 64.0f;
        out[pix * 3 + 0] = (dacc0 * ax * 2.0f + sacc0) * inv_s;
        out[pix * 3 + 1] = (dacc1 * ay * 2.0f + sacc1) * inv_s;
        out[pix * 3 + 2] = (dacc2 * az * 2.0f + sacc2) * inv_s;
    }
}

extern "C" void kernel_launch(void* const* d_in, const int* in_sizes, int n_in,
                              void* d_out, int out_size, void* d_ws, size_t ws_size,
                              hipStream_t stream) {
    const float* normal    = (const float*)d_in[0];
    const float* albedo    = (const float*)d_in[1];
    const float* roughness = (const float*)d_in[2];
    const float* points    = (const float*)d_in[3];
    const float* cam       = (const float*)d_in[4];
    const float* ldir      = (const float*)d_in[5];
    const float* dlight    = (const float*)d_in[6];
    const float* hdir      = (const float*)d_in[7];
    const float* slight    = (const float*)d_in[8];
    float* out = (float*)d_out;

    const int blocks = N_PIX / TILE;  // 8192
    shade_kernel<<<blocks, 256, 0, stream>>>(normal, albedo, roughness, points,
                                             cam, ldir, dlight, hdir, slight, out);
}